// Round 8
// baseline (257.555 us; speedup 1.0000x reference)
//
#include <hip/hip_runtime.h>
#include <math.h>

#define T_TOK 4096
#define HIDDEN 2048
#define NH 16
#define NKVH 2
#define HD 128
#define NSEG 8
#define QKV_N 2560   // 2048 q + 256 k + 256 v
#define ROW_Q 0
#define ROW_K 2048
#define ROW_V 2304

typedef __attribute__((ext_vector_type(8))) short bf16x8;
typedef __attribute__((ext_vector_type(4))) float f32x4;

__device__ __forceinline__ unsigned short f2bf(float f) {
    union { float f; unsigned u; } x; x.f = f;
    unsigned r = x.u + 0x7FFF + ((x.u >> 16) & 1);
    return (unsigned short)(r >> 16);
}
__device__ __forceinline__ float bf2f(unsigned short u) {
    union { unsigned u; float f; } x; x.u = ((unsigned)u) << 16;
    return x.f;
}
__device__ __forceinline__ void gload16(const void* g, void* l) {
    __builtin_amdgcn_global_load_lds(
        (const __attribute__((address_space(1))) unsigned int*)g,
        (__attribute__((address_space(3))) unsigned int*)l, 16, 0, 0);
}

// Raw barrier: memory clobber orders LDS/VMEM ops; register-only MFMA may
// still interleave with neighboring phases. vmcnt(N) is per-wave, so any
// counted wait MUST be immediately followed by a barrier before cross-wave
// staged data is read (R7 lesson).
#define BAR() asm volatile("s_barrier" ::: "memory")

// ---------- zero d_out (needed for split-K atomic accumulation) ----------
__global__ void zero_f32(float* __restrict__ p)
{
    int i = (blockIdx.x * 256 + threadIdx.x) * 4;
    *(float4*)&p[i] = float4{0.f, 0.f, 0.f, 0.f};
}

// ---------- fp32 -> bf16 ----------
__global__ void conv_bf16(const float* __restrict__ in, unsigned short* __restrict__ out, int n)
{
    int i = (blockIdx.x * 256 + threadIdx.x) * 4;
    if (i + 3 < n) {
        float4 v = *(const float4*)&in[i];
        ushort4 o;
        o.x = f2bf(v.x); o.y = f2bf(v.y); o.z = f2bf(v.z); o.w = f2bf(v.w);
        *(ushort4*)&out[i] = o;
    }
}

// ---------- packed Wq|Wk|Wv transpose: WT[n][k], n in [0,2560) ----------
__global__ void transpose_wqkv(const float* __restrict__ Wq, const float* __restrict__ Wk,
                               const float* __restrict__ Wv, unsigned short* __restrict__ WT)
{
    __shared__ float tile[32][33];
    const int n0 = blockIdx.x * 32, k0 = blockIdx.y * 32;
    const float* src; int col0, stride;
    if (n0 < ROW_K)      { src = Wq; col0 = n0;         stride = NH * HD; }
    else if (n0 < ROW_V) { src = Wk; col0 = n0 - ROW_K; stride = NKVH * HD; }
    else                 { src = Wv; col0 = n0 - ROW_V; stride = NKVH * HD; }
    const int c = threadIdx.x & 31, r0 = threadIdx.x >> 5;
    #pragma unroll
    for (int r = r0; r < 32; r += 8)
        tile[r][c] = src[(size_t)(k0 + r) * stride + col0 + c];
    __syncthreads();
    #pragma unroll
    for (int r = r0; r < 32; r += 8)
        WT[(size_t)(n0 + r) * HIDDEN + k0 + c] = f2bf(tile[c][r]);
}

// ---------- W [K][N] fp32 -> WT [N][K] bf16 (for Wo) ----------
__global__ void transpose_w(const float* __restrict__ W, unsigned short* __restrict__ WT,
                            int K, int N)
{
    __shared__ float tile[32][33];
    const int k0 = blockIdx.y * 32, n0 = blockIdx.x * 32;
    const int c = threadIdx.x & 31, r0 = threadIdx.x >> 5;
    #pragma unroll
    for (int r = r0; r < 32; r += 8)
        tile[r][c] = W[(size_t)(k0 + r) * N + n0 + c];
    __syncthreads();
    #pragma unroll
    for (int r = r0; r < 32; r += 8)
        WT[(size_t)(n0 + r) * K + k0 + c] = f2bf(tile[c][r]);
}

__global__ void pack_bias(const float* __restrict__ bq, const float* __restrict__ bk,
                          const float* __restrict__ bv, float* __restrict__ o)
{
    int i = blockIdx.x * 256 + threadIdx.x;
    if (i < ROW_K) o[i] = bq[i];
    else if (i < ROW_V) o[i] = bk[i - ROW_K];
    else if (i < QKV_N) o[i] = bv[i - ROW_V];
}

// ---------- RoPE on packed qkv (q scaled by 1/sqrt(D)), fp32 math ----------
__global__ void rope_kernel(unsigned short* __restrict__ qkv, const int* __restrict__ pos,
                            const float* __restrict__ invf)
{
    const int tok = blockIdx.x * 4 + (threadIdx.x >> 6);
    const int f = threadIdx.x & 63;
    const float p = (float)pos[tok];
    const float ang = p * invf[f];
    const float c = cosf(ang), s = sinf(ang);
    const float SC = 0.08838834764831845f;
    unsigned short* row = qkv + (size_t)tok * QKV_N;
    #pragma unroll
    for (int h = 0; h < NH; ++h) {
        unsigned short* u = row + h * HD;
        const float x1 = bf2f(u[f]), x2 = bf2f(u[f + 64]);
        u[f]      = f2bf((x1 * c - x2 * s) * SC);
        u[f + 64] = f2bf((x2 * c + x1 * s) * SC);
    }
    #pragma unroll
    for (int h = 0; h < NKVH; ++h) {
        unsigned short* u = row + ROW_K + h * HD;
        const float x1 = bf2f(u[f]), x2 = bf2f(u[f + 64]);
        u[f]      = f2bf(x1 * c - x2 * s);
        u[f + 64] = f2bf(x2 * c + x1 * s);
    }
}

// ============ 8-phase 256x256 MFMA GEMM (T3+T4+T5, T1), split-K capable ======
// C[M][N] = A[M][K] * BT[N][K]^T (+bias). BM=256, BN=256, BK=64, 8 waves (2m x 4n).
// K-range per block: [koff, koff+kspan), koff = blockIdx.y * kspan.
// MODE 0: bf16 out stride QKV_N, bias, V cols written transposed to vt
// MODE 1: f32 atomicAdd out stride HIDDEN, no bias (split-K accumulation)
template<int MODE>
__global__ __launch_bounds__(512, 2) void gemm8(const unsigned short* __restrict__ A,
                                                const unsigned short* __restrict__ BT,
                                                const float* __restrict__ bias,
                                                void* __restrict__ Cout,
                                                unsigned short* __restrict__ vt,
                                                int N, int K, int kspan)
{
    constexpr int NPH   = 2;
    constexpr int BHALF = 16384;
    constexpr int ABUF  = 32768;
    constexpr int BBUF  = 2 * BHALF;
    constexpr int BOFF  = 2 * ABUF;
    __shared__ __align__(16) unsigned char lds[BOFF + 2 * BBUF];

    const int tid = threadIdx.x, lane = tid & 63, w = tid >> 6;
    const int wm = w >> 2, wn = w & 3;
    const int lr = lane & 15, lk = lane >> 4;

    const int NTN = N / 256;
    const int cpx = gridDim.x >> 3;
    const int bid = blockIdx.x;
    const int wg = (bid & 7) * cpx + (bid >> 3);      // XCD swizzle (nwg % 8 == 0)
    const int brow = (wg / NTN) * 256, bcol = (wg % NTN) * 256;
    const int koff = blockIdx.y * kspan;

    const size_t aRow = (size_t)(brow + w * 16 + lr) * K + koff + lk * 8;
    const size_t bRow = (size_t)(bcol + w * 16 + lr) * K + koff + lk * 8;
    const int dst = w * 2048 + lane * 16;

    auto stA = [&](int kt, int h, int b) {
        const unsigned short* s = A + aRow + (size_t)h * 128 * K + kt * 64;
        unsigned char* d = lds + b * ABUF + h * 16384 + dst;
        gload16(s, d);
        gload16(s + 32, d + 1024);
    };
    auto stB = [&](int kt, int h, int b) {
        const unsigned short* s = BT + bRow + (size_t)h * 128 * K + kt * 64;
        unsigned char* d = lds + BOFF + b * BBUF + h * BHALF + dst;
        gload16(s, d);
        gload16(s + 32, d + 1024);
    };

    const int fragOff = lk * 256 + lr * 16;
    auto ldA = [&](int b, int mh, int m, int kk) -> bf16x8 {
        return *(const bf16x8*)(lds + b * ABUF + mh * 16384 + (wm * 4 + m) * 2048
                                + kk * 1024 + fragOff);
    };
    auto ldB = [&](int b, int nh, int n, int kk) -> bf16x8 {
        return *(const bf16x8*)(lds + BOFF + b * BBUF + nh * BHALF + (wn * 2 + n) * 2048
                                + kk * 1024 + fragOff);
    };

    f32x4 acc[8][4];
    #pragma unroll
    for (int i = 0; i < 8; ++i)
        #pragma unroll
        for (int j = 0; j < 4; ++j)
            acc[i][j] = f32x4{0.f, 0.f, 0.f, 0.f};

    const int NT = kspan >> 6;

    // prologue: K0 fully (4 half-tiles) + {A0,B0,B1} of K1
    stA(0, 0, 0); stA(0, 1, 0); stB(0, 0, 0); stB(0, 1, 0);
    stA(1, 0, 1); stB(1, 0, 1); stB(1, 1, 1);
    asm volatile("s_waitcnt vmcnt(6)" ::: "memory");
    BAR();

    for (int kt = 0; kt < NT; ++kt) {
        const int b = kt & 1;
        bf16x8 af[4][2], bfr[2][NPH][2];

        // ---- ph0: read A-h0 (8) + B-h0; stage A1(kt+1) -> buf b^1
        #pragma unroll
        for (int m = 0; m < 4; ++m) {
            af[m][0] = ldA(b, 0, m, 0);
            af[m][1] = ldA(b, 0, m, 1);
        }
        #pragma unroll
        for (int n = 0; n < NPH; ++n) {
            bfr[0][n][0] = ldB(b, 0, n, 0);
            bfr[0][n][1] = ldB(b, 0, n, 1);
        }
        if (kt + 1 < NT) stA(kt + 1, 1, b ^ 1);
        BAR();
        __builtin_amdgcn_s_setprio(1);
        #pragma unroll
        for (int m = 0; m < 4; ++m)
            #pragma unroll
            for (int n = 0; n < NPH; ++n)
                #pragma unroll
                for (int kk = 0; kk < 2; ++kk)
                    acc[m][n] = __builtin_amdgcn_mfma_f32_16x16x32_bf16(
                        af[m][kk], bfr[0][n][kk], acc[m][n], 0, 0, 0);
        __builtin_amdgcn_s_setprio(0);
        BAR();

        // ---- ph1: read B-h1; stage A0(kt+2) -> buf b
        #pragma unroll
        for (int n = 0; n < NPH; ++n) {
            bfr[1][n][0] = ldB(b, 1, n, 0);
            bfr[1][n][1] = ldB(b, 1, n, 1);
        }
        if (kt + 2 < NT) stA(kt + 2, 0, b);
        BAR();
        __builtin_amdgcn_s_setprio(1);
        #pragma unroll
        for (int m = 0; m < 4; ++m)
            #pragma unroll
            for (int n = 0; n < NPH; ++n)
                #pragma unroll
                for (int kk = 0; kk < 2; ++kk)
                    acc[m][NPH + n] = __builtin_amdgcn_mfma_f32_16x16x32_bf16(
                        af[m][kk], bfr[1][n][kk], acc[m][NPH + n], 0, 0, 0);
        __builtin_amdgcn_s_setprio(0);
        BAR();

        // ---- ph2: read A-h1 (8); stage B0(kt+2) -> buf b
        #pragma unroll
        for (int m = 0; m < 4; ++m) {
            af[m][0] = ldA(b, 1, m, 0);
            af[m][1] = ldA(b, 1, m, 1);
        }
        if (kt + 2 < NT) stB(kt + 2, 0, b);
        BAR();
        __builtin_amdgcn_s_setprio(1);
        #pragma unroll
        for (int m = 0; m < 4; ++m)
            #pragma unroll
            for (int n = 0; n < NPH; ++n)
                #pragma unroll
                for (int kk = 0; kk < 2; ++kk)
                    acc[4 + m][n] = __builtin_amdgcn_mfma_f32_16x16x32_bf16(
                        af[m][kk], bfr[0][n][kk], acc[4 + m][n], 0, 0, 0);
        __builtin_amdgcn_s_setprio(0);
        BAR();

        // ---- ph3: stage B1(kt+2) -> buf b; counted vmcnt (once per K-tile),
        //      immediately before the barrier (cross-wave safety).
        if (kt + 2 < NT) stB(kt + 2, 1, b);
        if (kt < NT - 2) asm volatile("s_waitcnt vmcnt(6)" ::: "memory");
        else             asm volatile("s_waitcnt vmcnt(0)" ::: "memory");
        BAR();
        __builtin_amdgcn_s_setprio(1);
        #pragma unroll
        for (int m = 0; m < 4; ++m)
            #pragma unroll
            for (int n = 0; n < NPH; ++n)
                #pragma unroll
                for (int kk = 0; kk < 2; ++kk)
                    acc[4 + m][NPH + n] = __builtin_amdgcn_mfma_f32_16x16x32_bf16(
                        af[m][kk], bfr[1][n][kk], acc[4 + m][NPH + n], 0, 0, 0);
        __builtin_amdgcn_s_setprio(0);
        BAR();
    }

    // epilogue
    #pragma unroll
    for (int ms = 0; ms < 8; ++ms) {
        const int row = brow + (ms >> 2) * 128 + wm * 64 + (ms & 3) * 16 + lk * 4;
        #pragma unroll
        for (int ns = 0; ns < 4; ++ns) {
            const int col = bcol + (ns >> 1) * 128 + wn * 32 + (ns & 1) * 16 + lr;
            if constexpr (MODE == 0) {
                const float bbv = bias[col];
                if (col >= ROW_V) {
                    ushort4 o;
                    o.x = f2bf(acc[ms][ns][0] + bbv);
                    o.y = f2bf(acc[ms][ns][1] + bbv);
                    o.z = f2bf(acc[ms][ns][2] + bbv);
                    o.w = f2bf(acc[ms][ns][3] + bbv);
                    *(ushort4*)&vt[(size_t)(col - ROW_V) * T_TOK + row] = o;
                } else {
                    #pragma unroll
                    for (int j = 0; j < 4; ++j)
                        ((unsigned short*)Cout)[(size_t)(row + j) * QKV_N + col] = f2bf(acc[ms][ns][j] + bbv);
                }
            } else {
                #pragma unroll
                for (int j = 0; j < 4; ++j)
                    atomicAdd(&((float*)Cout)[(size_t)(row + j) * HIDDEN + col], acc[ms][ns][j]);
            }
        }
    }
}

// ---------- varlen causal GQA flash attention ----------
// Swapped-operand MFMA: S^T = mfma(K,Q), O^T = mfma(V^T, P^T). P in registers.
__global__ __launch_bounds__(256) void attn_mfma(const unsigned short* __restrict__ qkv,
                                                 const unsigned short* __restrict__ vt,
                                                 const int* __restrict__ cu,
                                                 unsigned short* __restrict__ ob)
{
    __shared__ __align__(16) unsigned short Klds[2][4096]; // [st2][kk4][lk4][lr16][8]
    __shared__ __align__(16) unsigned short Vlds[2][4096]; // [dt8][lk4][lr16][8]

    const int tid = threadIdx.x;
    const int l = tid & 63, w = tid >> 6;
    const int lr = l & 15, lk = l >> 4;

    const int bid = blockIdx.x;
    const int h = bid >> 6;
    const int qb = (bid + 37 * (bid >> 6)) & 63;   // balance swizzle
    const int q0 = qb * 64;
    const int kvh = h >> 3;

    bf16x8 aq[4];
    #pragma unroll
    for (int kk = 0; kk < 4; ++kk)
        aq[kk] = *(const bf16x8*)&qkv[(size_t)(q0 + w * 16 + lr) * QKV_N + h * HD + kk * 32 + lk * 8];

    const int qg = q0 + w * 16 + lr;
    int seg_lo = 0, seg_last = 0, sb = 0;
    #pragma unroll
    for (int x = 1; x < NSEG; ++x) {
        const int cx = cu[x];
        seg_lo   = (cx <= qg)      ? cx : seg_lo;
        seg_last = (cx <= q0 + 63) ? cx : seg_last;
        sb       = (cx <= q0)      ? cx : sb;
    }
    sb &= ~31;

    const int lr_s = tid & 15, lk_s = (tid >> 4) & 3, w_s = tid >> 6;
    const unsigned short* kSrc0 = qkv + (size_t)(sb + lr_s) * QKV_N + ROW_K + kvh * HD + w_s * 32 + lk_s * 8;
    const unsigned short* kSrc1 = kSrc0 + (size_t)16 * QKV_N;
    const unsigned short* vSrc0 = vt + (size_t)(kvh * HD + w_s * 16 + lr_s) * T_TOK + sb + lk_s * 8;
    const unsigned short* vSrc1 = vSrc0 + (size_t)64 * T_TOK;

    float m_r = -1e30f, l_r = 0.f;
    f32x4 oacc[8];
    #pragma unroll
    for (int d = 0; d < 8; ++d) oacc[d] = f32x4{0.f, 0.f, 0.f, 0.f};

    const int nt = ((q0 + 63 - sb) >> 5) + 1;

    gload16(kSrc0, &Klds[0][tid * 8]);
    gload16(kSrc1, &Klds[0][2048 + tid * 8]);
    gload16(vSrc0, &Vlds[0][tid * 8]);
    gload16(vSrc1, &Vlds[0][2048 + tid * 8]);
    __syncthreads();

    int buf = 0;
    for (int t = 0; t < nt; ++t) {
        const int s0 = sb + t * 32;
        kSrc0 += 32 * QKV_N; kSrc1 += 32 * QKV_N;
        vSrc0 += 32;         vSrc1 += 32;
        if (t + 1 < nt) {
            gload16(kSrc0, &Klds[buf ^ 1][tid * 8]);
            gload16(kSrc1, &Klds[buf ^ 1][2048 + tid * 8]);
            gload16(vSrc0, &Vlds[buf ^ 1][tid * 8]);
            gload16(vSrc1, &Vlds[buf ^ 1][2048 + tid * 8]);
        }

        f32x4 sacc[2];
        sacc[0] = f32x4{0.f, 0.f, 0.f, 0.f};
        sacc[1] = f32x4{0.f, 0.f, 0.f, 0.f};
        #pragma unroll
        for (int kk = 0; kk < 4; ++kk) {
            bf16x8 ak0 = *(const bf16x8*)&Klds[buf][kk * 512 + lk * 128 + lr * 8];
            bf16x8 ak1 = *(const bf16x8*)&Klds[buf][2048 + kk * 512 + lk * 128 + lr * 8];
            sacc[0] = __builtin_amdgcn_mfma_f32_16x16x32_bf16(ak0, aq[kk], sacc[0], 0, 0, 0);
            sacc[1] = __builtin_amdgcn_mfma_f32_16x16x32_bf16(ak1, aq[kk], sacc[1], 0, 0, 0);
        }

        float x[8];
        #pragma unroll
        for (int st = 0; st < 2; ++st)
            #pragma unroll
            for (int jj = 0; jj < 4; ++jj)
                x[st * 4 + jj] = sacc[st][jj];

        const bool fast = (s0 >= seg_last) && (s0 + 31 <= q0);
        if (!fast) {
            #pragma unroll
            for (int st = 0; st < 2; ++st)
                #pragma unroll
                for (int jj = 0; jj < 4; ++jj) {
                    const int sg = s0 + st * 16 + lk * 4 + jj;
                    const bool vld = (sg >= seg_lo) && (sg <= qg);
                    x[st * 4 + jj] = vld ? x[st * 4 + jj] : -3e38f;
                }
        }

        float mx = fmaxf(fmaxf(fmaxf(x[0], x[1]), fmaxf(x[2], x[3])),
                         fmaxf(fmaxf(x[4], x[5]), fmaxf(x[6], x[7])));
        mx = fmaxf(mx, __shfl_xor(mx, 16));
        mx = fmaxf(mx, __shfl_xor(mx, 32));
        const float mn = fmaxf(m_r, mx);
        const float al = __expf(m_r - mn);
        float p[8], ps = 0.f;
        #pragma unroll
        for (int i = 0; i < 8; ++i) { p[i] = __expf(x[i] - mn); ps += p[i]; }
        ps += __shfl_xor(ps, 16);
        ps += __shfl_xor(ps, 32);
        l_r = l_r * al + ps;
        m_r = mn;

        #pragma unroll
        for (int dt = 0; dt < 8; ++dt) {
            oacc[dt][0] *= al; oacc[dt][1] *= al;
            oacc[dt][2] *= al; oacc[dt][3] *= al;
        }

        int u00 = ((int)f2bf(p[1]) << 16) | f2bf(p[0]);
        int u01 = ((int)f2bf(p[3]) << 16) | f2bf(p[2]);
        int u10 = ((int)f2bf(p[5]) << 16) | f2bf(p[4]);
        int u11 = ((int)f2bf(p[7]) << 16) | f2bf(p[6]);

        const int srcA = (lk & 1) * 32 + lr;
        const int srcB = srcA + 16;
        const bool hi = (lk & 2) != 0;
        int a0 = __shfl(u00, srcA), b0 = __shfl(u10, srcA);
        int a1 = __shfl(u01, srcA), b1 = __shfl(u11, srcA);
        int a2 = __shfl(u00, srcB), b2 = __shfl(u10, srcB);
        int a3 = __shfl(u01, srcB), b3 = __shfl(u11, srcB);
        union { int wds[4]; bf16x8 v; } pf;
        pf.wds[0] = hi ? b0 : a0;
        pf.wds[1] = hi ? b1 : a1;
        pf.wds[2] = hi ? b2 : a2;
        pf.wds[3] = hi ? b3 : a3;

        #pragma unroll
        for (int dt = 0; dt < 8; ++dt) {
            bf16x8 av = *(const bf16x8*)&Vlds[buf][dt * 512 + lk * 128 + lr * 8];
            oacc[dt] = __builtin_amdgcn_mfma_f32_16x16x32_bf16(av, pf.v, oacc[dt], 0, 0, 0);
        }
        __syncthreads();
        buf ^= 1;
    }

    const float inv = 1.f / l_r;
    #pragma unroll
    for (int dt = 0; dt < 8; ++dt) {
        ushort4 o;
        o.x = f2bf(oacc[dt][0] * inv);
        o.y = f2bf(oacc[dt][1] * inv);
        o.z = f2bf(oacc[dt][2] * inv);
        o.w = f2bf(oacc[dt][3] * inv);
        *(ushort4*)&ob[(size_t)qg * (NH * HD) + h * HD + dt * 16 + lk * 4] = o;
    }
}

extern "C" void kernel_launch(void* const* d_in, const int* in_sizes, int n_in,
                              void* d_out, int out_size, void* d_ws, size_t ws_size,
                              hipStream_t stream)
{
    const float* hs       = (const float*)d_in[0];
    const int*   pos      = (const int*)d_in[1];
    const int*   cu       = (const int*)d_in[2];
    const float* inv_freq = (const float*)d_in[3];
    const float* Wq       = (const float*)d_in[4];
    const float* bq       = (const float*)d_in[5];
    const float* Wk       = (const float*)d_in[6];
    const float* bk       = (const float*)d_in[7];
    const float* Wv       = (const float*)d_in[8];
    const float* bv       = (const float*)d_in[9];
    const float* Wo       = (const float*)d_in[10];
    float* out = (float*)d_out;

    unsigned short* hsb   = (unsigned short*)d_ws;          //  8,388,608
    unsigned short* wqkvT = hsb + 8388608;                  //  5,242,880
    unsigned short* wot   = wqkvT + 5242880;                //  4,194,304
    unsigned short* qkvb  = wot + 4194304;                  // 10,485,760
    unsigned short* vtb   = qkvb + 10485760;                //  1,048,576
    unsigned short* obb   = vtb + 1048576;                  //  8,388,608
    float* bqkv = (float*)(obb + 8388608);                  //  2,560 floats

    zero_f32<<<(T_TOK * HIDDEN) / 1024, 256, 0, stream>>>(out);
    conv_bf16<<<8192, 256, 0, stream>>>(hs, hsb, T_TOK * HIDDEN);
    transpose_wqkv<<<dim3(QKV_N / 32, HIDDEN / 32), 256, 0, stream>>>(Wq, Wk, Wv, wqkvT);
    transpose_w<<<dim3(HIDDEN / 32, HIDDEN / 32), 256, 0, stream>>>(Wo, wot, NH * HD, HIDDEN);
    pack_bias<<<10, 256, 0, stream>>>(bq, bk, bv, bqkv);

    gemm8<0><<<dim3((T_TOK / 256) * (QKV_N / 256), 1), 512, 0, stream>>>(
        hsb, wqkvT, bqkv, qkvb, vtb, QKV_N, HIDDEN, HIDDEN);

    rope_kernel<<<dim3(T_TOK / 4), 256, 0, stream>>>(qkvb, pos, inv_freq);

    attn_mfma<<<dim3(64 * NH), 256, 0, stream>>>(qkvb, vtb, cu, obb);

    gemm8<1><<<dim3((T_TOK / 256) * (HIDDEN / 256), 2), 512, 0, stream>>>(
        obb, wot, nullptr, out, nullptr, HIDDEN, NH * HD, (NH * HD) / 2);
}

// Round 9
// 228.316 us; speedup vs baseline: 1.1281x; 1.1281x over previous
//
#include <hip/hip_runtime.h>
#include <math.h>

#define T_TOK 4096
#define HIDDEN 2048
#define NH 16
#define NKVH 2
#define HD 128
#define NSEG 8
#define QKV_N 2560   // 2048 q + 256 k + 256 v
#define ROW_Q 0
#define ROW_K 2048
#define ROW_V 2304

typedef __attribute__((ext_vector_type(8))) short bf16x8;
typedef __attribute__((ext_vector_type(4))) float f32x4;

__device__ __forceinline__ unsigned short f2bf(float f) {
    union { float f; unsigned u; } x; x.f = f;
    unsigned r = x.u + 0x7FFF + ((x.u >> 16) & 1);
    return (unsigned short)(r >> 16);
}
__device__ __forceinline__ float bf2f(unsigned short u) {
    union { unsigned u; float f; } x; x.u = ((unsigned)u) << 16;
    return x.f;
}
__device__ __forceinline__ void gload16(const void* g, void* l) {
    __builtin_amdgcn_global_load_lds(
        (const __attribute__((address_space(1))) unsigned int*)g,
        (__attribute__((address_space(3))) unsigned int*)l, 16, 0, 0);
}

// Raw barrier: memory clobber orders LDS/VMEM ops; register-only MFMA may
// interleave with neighboring phases. vmcnt(N) is per-wave, so every counted
// wait sits immediately before a barrier (R7 lesson).
#define BAR() asm volatile("s_barrier" ::: "memory")

// ---------- fp32 -> bf16 ----------
__global__ void conv_bf16(const float* __restrict__ in, unsigned short* __restrict__ out, int n)
{
    int i = (blockIdx.x * 256 + threadIdx.x) * 4;
    if (i + 3 < n) {
        float4 v = *(const float4*)&in[i];
        ushort4 o;
        o.x = f2bf(v.x); o.y = f2bf(v.y); o.z = f2bf(v.z); o.w = f2bf(v.w);
        *(ushort4*)&out[i] = o;
    }
}

// ---------- merged weight transpose: Wq|Wk|Wv -> wqkvT, Wo -> wot ----------
__global__ void transpose_all(const float* __restrict__ Wq, const float* __restrict__ Wk,
                              const float* __restrict__ Wv, const float* __restrict__ Wo,
                              unsigned short* __restrict__ wqkvT, unsigned short* __restrict__ wot)
{
    __shared__ float tile[32][33];
    const int n0 = blockIdx.x * 32, k0 = blockIdx.y * 32;
    const float* src; int col0, stride; unsigned short* dst; int dn0;
    if (n0 < ROW_K)       { src = Wq; col0 = n0;          stride = NH * HD;   dst = wqkvT; dn0 = n0; }
    else if (n0 < ROW_V)  { src = Wk; col0 = n0 - ROW_K;  stride = NKVH * HD; dst = wqkvT; dn0 = n0; }
    else if (n0 < QKV_N)  { src = Wv; col0 = n0 - ROW_V;  stride = NKVH * HD; dst = wqkvT; dn0 = n0; }
    else                  { src = Wo; col0 = n0 - QKV_N;  stride = HIDDEN;    dst = wot;   dn0 = n0 - QKV_N; }
    const int c = threadIdx.x & 31, r0 = threadIdx.x >> 5;
    #pragma unroll
    for (int r = r0; r < 32; r += 8)
        tile[r][c] = src[(size_t)(k0 + r) * stride + col0 + c];
    __syncthreads();
    #pragma unroll
    for (int r = r0; r < 32; r += 8)
        dst[(size_t)(dn0 + r) * HIDDEN + k0 + c] = f2bf(tile[c][r]);
}

__global__ void pack_bias(const float* __restrict__ bq, const float* __restrict__ bk,
                          const float* __restrict__ bv, float* __restrict__ o)
{
    int i = blockIdx.x * 256 + threadIdx.x;
    if (i < ROW_K) o[i] = bq[i];
    else if (i < ROW_V) o[i] = bk[i - ROW_K];
    else if (i < QKV_N) o[i] = bv[i - ROW_V];
}

// ---------- RoPE on K only (Q roped in-register inside attn) ----------
__global__ void rope_k(unsigned short* __restrict__ qkv, const int* __restrict__ pos,
                       const float* __restrict__ invf)
{
    const int tok = blockIdx.x * 2 + (threadIdx.x >> 7);
    const int h = (threadIdx.x >> 6) & 1;
    const int f = threadIdx.x & 63;
    const float p = (float)pos[tok];
    const float ang = p * invf[f];
    const float c = cosf(ang), s = sinf(ang);
    unsigned short* u = qkv + (size_t)tok * QKV_N + ROW_K + h * HD;
    const float x1 = bf2f(u[f]), x2 = bf2f(u[f + 64]);
    u[f]      = f2bf(x1 * c - x2 * s);
    u[f + 64] = f2bf(x2 * c + x1 * s);
}

// ============ 8-phase 256xBN MFMA GEMM (T3+T4+T5, T1) — R6-proven ============
// C[M][N] = A[M][K] * BT[N][K]^T (+bias). BM=256, BK=64, 8 waves (2m x 4n).
// MODE 0: BN=256, bf16 out stride QKV_N, bias, V cols written transposed to vt
// MODE 1: BN=128, f32 out stride HIDDEN, no bias
template<int MODE>
__global__ __launch_bounds__(512, 2) void gemm8(const unsigned short* __restrict__ A,
                                                const unsigned short* __restrict__ BT,
                                                const float* __restrict__ bias,
                                                void* __restrict__ Cout,
                                                unsigned short* __restrict__ vt,
                                                int N, int K)
{
    constexpr int BN    = (MODE == 0) ? 256 : 128;
    constexpr int NPH   = (MODE == 0) ? 2 : 1;
    constexpr int BHALF = (MODE == 0) ? 16384 : 8192;
    constexpr int ABUF  = 32768;
    constexpr int BBUF  = 2 * BHALF;
    constexpr int BOFF  = 2 * ABUF;
    __shared__ __align__(16) unsigned char lds[BOFF + 2 * BBUF];

    const int tid = threadIdx.x, lane = tid & 63, w = tid >> 6;
    const int wm = w >> 2, wn = w & 3;
    const int lr = lane & 15, lk = lane >> 4;

    const int NTN = N / BN;
    const int cpx = gridDim.x >> 3;
    const int bid = blockIdx.x;
    const int wg = (bid & 7) * cpx + (bid >> 3);      // XCD swizzle (nwg % 8 == 0)
    const int brow = (wg / NTN) * 256, bcol = (wg % NTN) * BN;

    const size_t aRow = (size_t)(brow + w * 16 + lr) * K + lk * 8;
    size_t bRow;
    if constexpr (MODE == 0) bRow = (size_t)(bcol + w * 16 + lr) * K + lk * 8;
    else                     bRow = (size_t)(bcol + (w >> 1) * 16 + lr) * K + ((w & 1) * 4 + lk) * 8;
    const int dstA = w * 2048 + lane * 16;
    const int dstB = (MODE == 0) ? dstA : (w * 1024 + lane * 16);

    auto stA = [&](int kt, int h, int b) {
        const unsigned short* s = A + aRow + (size_t)h * 128 * K + kt * 64;
        unsigned char* d = lds + b * ABUF + h * 16384 + dstA;
        gload16(s, d);
        gload16(s + 32, d + 1024);
    };
    auto stB = [&](int kt, int h, int b) {
        const unsigned short* s = BT + bRow + (size_t)h * (BN / 2) * K + kt * 64;
        unsigned char* d = lds + BOFF + b * BBUF + h * BHALF + dstB;
        gload16(s, d);
        if constexpr (MODE == 0) gload16(s + 32, d + 1024);
    };

    const int fragOff = lk * 256 + lr * 16;
    auto ldA = [&](int b, int mh, int m, int kk) -> bf16x8 {
        return *(const bf16x8*)(lds + b * ABUF + mh * 16384 + (wm * 4 + m) * 2048
                                + kk * 1024 + fragOff);
    };
    auto ldB = [&](int b, int nh, int n, int kk) -> bf16x8 {
        const int sub = (MODE == 0) ? (wn * 2 + n) : wn;
        return *(const bf16x8*)(lds + BOFF + b * BBUF + nh * BHALF + sub * 2048
                                + kk * 1024 + fragOff);
    };

    f32x4 acc[8][2 * NPH];
    #pragma unroll
    for (int i = 0; i < 8; ++i)
        #pragma unroll
        for (int j = 0; j < 2 * NPH; ++j)
            acc[i][j] = f32x4{0.f, 0.f, 0.f, 0.f};

    const int NT = K >> 6;

    stA(0, 0, 0); stA(0, 1, 0); stB(0, 0, 0); stB(0, 1, 0);
    stA(1, 0, 1); stB(1, 0, 1); stB(1, 1, 1);
    if constexpr (MODE == 0) asm volatile("s_waitcnt vmcnt(6)" ::: "memory");
    else                     asm volatile("s_waitcnt vmcnt(4)" ::: "memory");
    BAR();

    for (int kt = 0; kt < NT; ++kt) {
        const int b = kt & 1;
        bf16x8 af[4][2], bfr[2][NPH][2];

        // ---- ph0: read A-h0 + B-h0; stage A1(kt+1) -> buf b^1
        #pragma unroll
        for (int m = 0; m < 4; ++m) {
            af[m][0] = ldA(b, 0, m, 0);
            af[m][1] = ldA(b, 0, m, 1);
        }
        #pragma unroll
        for (int n = 0; n < NPH; ++n) {
            bfr[0][n][0] = ldB(b, 0, n, 0);
            bfr[0][n][1] = ldB(b, 0, n, 1);
        }
        if (kt + 1 < NT) stA(kt + 1, 1, b ^ 1);
        BAR();
        __builtin_amdgcn_s_setprio(1);
        #pragma unroll
        for (int m = 0; m < 4; ++m)
            #pragma unroll
            for (int n = 0; n < NPH; ++n)
                #pragma unroll
                for (int kk = 0; kk < 2; ++kk)
                    acc[m][n] = __builtin_amdgcn_mfma_f32_16x16x32_bf16(
                        af[m][kk], bfr[0][n][kk], acc[m][n], 0, 0, 0);
        __builtin_amdgcn_s_setprio(0);
        BAR();

        // ---- ph1: read B-h1; stage A0(kt+2) -> buf b
        #pragma unroll
        for (int n = 0; n < NPH; ++n) {
            bfr[1][n][0] = ldB(b, 1, n, 0);
            bfr[1][n][1] = ldB(b, 1, n, 1);
        }
        if (kt + 2 < NT) stA(kt + 2, 0, b);
        BAR();
        __builtin_amdgcn_s_setprio(1);
        #pragma unroll
        for (int m = 0; m < 4; ++m)
            #pragma unroll
            for (int n = 0; n < NPH; ++n)
                #pragma unroll
                for (int kk = 0; kk < 2; ++kk)
                    acc[m][NPH + n] = __builtin_amdgcn_mfma_f32_16x16x32_bf16(
                        af[m][kk], bfr[1][n][kk], acc[m][NPH + n], 0, 0, 0);
        __builtin_amdgcn_s_setprio(0);
        BAR();

        // ---- ph2: read A-h1; stage B0(kt+2) -> buf b
        #pragma unroll
        for (int m = 0; m < 4; ++m) {
            af[m][0] = ldA(b, 1, m, 0);
            af[m][1] = ldA(b, 1, m, 1);
        }
        if (kt + 2 < NT) stB(kt + 2, 0, b);
        BAR();
        __builtin_amdgcn_s_setprio(1);
        #pragma unroll
        for (int m = 0; m < 4; ++m)
            #pragma unroll
            for (int n = 0; n < NPH; ++n)
                #pragma unroll
                for (int kk = 0; kk < 2; ++kk)
                    acc[4 + m][n] = __builtin_amdgcn_mfma_f32_16x16x32_bf16(
                        af[m][kk], bfr[0][n][kk], acc[4 + m][n], 0, 0, 0);
        __builtin_amdgcn_s_setprio(0);
        BAR();

        // ---- ph3: stage B1(kt+2) -> buf b; counted vmcnt just before barrier
        if (kt + 2 < NT) stB(kt + 2, 1, b);
        if (kt < NT - 2) {
            if constexpr (MODE == 0) asm volatile("s_waitcnt vmcnt(6)" ::: "memory");
            else                     asm volatile("s_waitcnt vmcnt(4)" ::: "memory");
        } else {
            asm volatile("s_waitcnt vmcnt(0)" ::: "memory");
        }
        BAR();
        __builtin_amdgcn_s_setprio(1);
        #pragma unroll
        for (int m = 0; m < 4; ++m)
            #pragma unroll
            for (int n = 0; n < NPH; ++n)
                #pragma unroll
                for (int kk = 0; kk < 2; ++kk)
                    acc[4 + m][NPH + n] = __builtin_amdgcn_mfma_f32_16x16x32_bf16(
                        af[m][kk], bfr[1][n][kk], acc[4 + m][NPH + n], 0, 0, 0);
        __builtin_amdgcn_s_setprio(0);
        BAR();
    }

    #pragma unroll
    for (int ms = 0; ms < 8; ++ms) {
        const int row = brow + (ms >> 2) * 128 + wm * 64 + (ms & 3) * 16 + lk * 4;
        #pragma unroll
        for (int ns = 0; ns < 2 * NPH; ++ns) {
            int col;
            if constexpr (MODE == 0)
                col = bcol + (ns >> 1) * 128 + wn * 32 + (ns & 1) * 16 + lr;
            else
                col = bcol + ns * 64 + wn * 16 + lr;
            const float bbv = (MODE == 0) ? bias[col] : 0.f;
            if (MODE == 0 && col >= ROW_V) {
                ushort4 o;
                o.x = f2bf(acc[ms][ns][0] + bbv);
                o.y = f2bf(acc[ms][ns][1] + bbv);
                o.z = f2bf(acc[ms][ns][2] + bbv);
                o.w = f2bf(acc[ms][ns][3] + bbv);
                *(ushort4*)&vt[(size_t)(col - ROW_V) * T_TOK + row] = o;
            } else {
                #pragma unroll
                for (int j = 0; j < 4; ++j) {
                    const float vv = acc[ms][ns][j] + bbv;
                    if (MODE == 0)
                        ((unsigned short*)Cout)[(size_t)(row + j) * QKV_N + col] = f2bf(vv);
                    else
                        ((float*)Cout)[(size_t)(row + j) * HIDDEN + col] = vv;
                }
            }
        }
    }
}

// ---------- varlen causal GQA flash attention (fused Q-RoPE) ----------
// Swapped-operand MFMA: S^T = mfma(K,Q), O^T = mfma(V^T, P^T). P in registers.
// Q fragments hold (d, d+64) pairs in-lane: (aq0,aq2) and (aq1,aq3) -> RoPE in reg.
__global__ __launch_bounds__(256) void attn_mfma(const unsigned short* __restrict__ qkv,
                                                 const unsigned short* __restrict__ vt,
                                                 const int* __restrict__ cu,
                                                 const int* __restrict__ pos,
                                                 const float* __restrict__ invf,
                                                 unsigned short* __restrict__ ob)
{
    __shared__ __align__(16) unsigned short Klds[2][4096]; // [st2][kk4][lk4][lr16][8]
    __shared__ __align__(16) unsigned short Vlds[2][4096]; // [dt8][lk4][lr16][8]

    const int tid = threadIdx.x;
    const int l = tid & 63, w = tid >> 6;
    const int lr = l & 15, lk = l >> 4;

    const int bid = blockIdx.x;
    const int h = bid >> 6;
    const int qb = (bid + 37 * (bid >> 6)) & 63;   // balance swizzle
    const int q0 = qb * 64;
    const int kvh = h >> 3;
    const int qg = q0 + w * 16 + lr;               // this lane's q-row

    bf16x8 aq[4];
    #pragma unroll
    for (int kk = 0; kk < 4; ++kk)
        aq[kk] = *(const bf16x8*)&qkv[(size_t)qg * QKV_N + h * HD + kk * 32 + lk * 8];

    // fused Q-RoPE + 1/sqrt(D) scale, fp32 math (same rounding chain as before)
    {
        const float p = (float)pos[qg];
        const float SC = 0.08838834764831845f;
        #pragma unroll
        for (int j = 0; j < 8; ++j) {
            const float a1 = p * invf[lk * 8 + j];
            const float a2 = p * invf[32 + lk * 8 + j];
            const float c0 = cosf(a1), s0 = sinf(a1);
            const float c1 = cosf(a2), s1 = sinf(a2);
            const float x0 = bf2f((unsigned short)aq[0][j]);
            const float x1 = bf2f((unsigned short)aq[1][j]);
            const float x2 = bf2f((unsigned short)aq[2][j]);
            const float x3 = bf2f((unsigned short)aq[3][j]);
            aq[0][j] = (short)f2bf((x0 * c0 - x2 * s0) * SC);
            aq[2][j] = (short)f2bf((x2 * c0 + x0 * s0) * SC);
            aq[1][j] = (short)f2bf((x1 * c1 - x3 * s1) * SC);
            aq[3][j] = (short)f2bf((x3 * c1 + x1 * s1) * SC);
        }
    }

    int seg_lo = 0, seg_last = 0, sb = 0;
    #pragma unroll
    for (int x = 1; x < NSEG; ++x) {
        const int cx = cu[x];
        seg_lo   = (cx <= qg)      ? cx : seg_lo;
        seg_last = (cx <= q0 + 63) ? cx : seg_last;
        sb       = (cx <= q0)      ? cx : sb;
    }
    sb &= ~31;

    const int lr_s = tid & 15, lk_s = (tid >> 4) & 3, w_s = tid >> 6;
    const unsigned short* kSrc0 = qkv + (size_t)(sb + lr_s) * QKV_N + ROW_K + kvh * HD + w_s * 32 + lk_s * 8;
    const unsigned short* kSrc1 = kSrc0 + (size_t)16 * QKV_N;
    const unsigned short* vSrc0 = vt + (size_t)(kvh * HD + w_s * 16 + lr_s) * T_TOK + sb + lk_s * 8;
    const unsigned short* vSrc1 = vSrc0 + (size_t)64 * T_TOK;

    float m_r = -1e30f, l_r = 0.f;
    f32x4 oacc[8];
    #pragma unroll
    for (int d = 0; d < 8; ++d) oacc[d] = f32x4{0.f, 0.f, 0.f, 0.f};

    const int nt = ((q0 + 63 - sb) >> 5) + 1;

    gload16(kSrc0, &Klds[0][tid * 8]);
    gload16(kSrc1, &Klds[0][2048 + tid * 8]);
    gload16(vSrc0, &Vlds[0][tid * 8]);
    gload16(vSrc1, &Vlds[0][2048 + tid * 8]);
    __syncthreads();

    int buf = 0;
    for (int t = 0; t < nt; ++t) {
        const int s0 = sb + t * 32;
        kSrc0 += 32 * QKV_N; kSrc1 += 32 * QKV_N;
        vSrc0 += 32;         vSrc1 += 32;
        if (t + 1 < nt) {
            gload16(kSrc0, &Klds[buf ^ 1][tid * 8]);
            gload16(kSrc1, &Klds[buf ^ 1][2048 + tid * 8]);
            gload16(vSrc0, &Vlds[buf ^ 1][tid * 8]);
            gload16(vSrc1, &Vlds[buf ^ 1][2048 + tid * 8]);
        }

        f32x4 sacc[2];
        sacc[0] = f32x4{0.f, 0.f, 0.f, 0.f};
        sacc[1] = f32x4{0.f, 0.f, 0.f, 0.f};
        #pragma unroll
        for (int kk = 0; kk < 4; ++kk) {
            bf16x8 ak0 = *(const bf16x8*)&Klds[buf][kk * 512 + lk * 128 + lr * 8];
            bf16x8 ak1 = *(const bf16x8*)&Klds[buf][2048 + kk * 512 + lk * 128 + lr * 8];
            sacc[0] = __builtin_amdgcn_mfma_f32_16x16x32_bf16(ak0, aq[kk], sacc[0], 0, 0, 0);
            sacc[1] = __builtin_amdgcn_mfma_f32_16x16x32_bf16(ak1, aq[kk], sacc[1], 0, 0, 0);
        }

        float x[8];
        #pragma unroll
        for (int st = 0; st < 2; ++st)
            #pragma unroll
            for (int jj = 0; jj < 4; ++jj)
                x[st * 4 + jj] = sacc[st][jj];

        const bool fast = (s0 >= seg_last) && (s0 + 31 <= q0);
        if (!fast) {
            #pragma unroll
            for (int st = 0; st < 2; ++st)
                #pragma unroll
                for (int jj = 0; jj < 4; ++jj) {
                    const int sg = s0 + st * 16 + lk * 4 + jj;
                    const bool vld = (sg >= seg_lo) && (sg <= qg);
                    x[st * 4 + jj] = vld ? x[st * 4 + jj] : -3e38f;
                }
        }

        float mx = fmaxf(fmaxf(fmaxf(x[0], x[1]), fmaxf(x[2], x[3])),
                         fmaxf(fmaxf(x[4], x[5]), fmaxf(x[6], x[7])));
        mx = fmaxf(mx, __shfl_xor(mx, 16));
        mx = fmaxf(mx, __shfl_xor(mx, 32));
        const float mn = fmaxf(m_r, mx);
        const float al = __expf(m_r - mn);
        float p[8], ps = 0.f;
        #pragma unroll
        for (int i = 0; i < 8; ++i) { p[i] = __expf(x[i] - mn); ps += p[i]; }
        ps += __shfl_xor(ps, 16);
        ps += __shfl_xor(ps, 32);
        l_r = l_r * al + ps;
        m_r = mn;

        #pragma unroll
        for (int dt = 0; dt < 8; ++dt) {
            oacc[dt][0] *= al; oacc[dt][1] *= al;
            oacc[dt][2] *= al; oacc[dt][3] *= al;
        }

        int u00 = ((int)f2bf(p[1]) << 16) | f2bf(p[0]);
        int u01 = ((int)f2bf(p[3]) << 16) | f2bf(p[2]);
        int u10 = ((int)f2bf(p[5]) << 16) | f2bf(p[4]);
        int u11 = ((int)f2bf(p[7]) << 16) | f2bf(p[6]);

        const int srcA = (lk & 1) * 32 + lr;
        const int srcB = srcA + 16;
        const bool hi = (lk & 2) != 0;
        int a0 = __shfl(u00, srcA), b0 = __shfl(u10, srcA);
        int a1 = __shfl(u01, srcA), b1 = __shfl(u11, srcA);
        int a2 = __shfl(u00, srcB), b2 = __shfl(u10, srcB);
        int a3 = __shfl(u01, srcB), b3 = __shfl(u11, srcB);
        union { int wds[4]; bf16x8 v; } pf;
        pf.wds[0] = hi ? b0 : a0;
        pf.wds[1] = hi ? b1 : a1;
        pf.wds[2] = hi ? b2 : a2;
        pf.wds[3] = hi ? b3 : a3;

        #pragma unroll
        for (int dt = 0; dt < 8; ++dt) {
            bf16x8 av = *(const bf16x8*)&Vlds[buf][dt * 512 + lk * 128 + lr * 8];
            oacc[dt] = __builtin_amdgcn_mfma_f32_16x16x32_bf16(av, pf.v, oacc[dt], 0, 0, 0);
        }
        __syncthreads();
        buf ^= 1;
    }

    const float inv = 1.f / l_r;
    #pragma unroll
    for (int dt = 0; dt < 8; ++dt) {
        ushort4 o;
        o.x = f2bf(oacc[dt][0] * inv);
        o.y = f2bf(oacc[dt][1] * inv);
        o.z = f2bf(oacc[dt][2] * inv);
        o.w = f2bf(oacc[dt][3] * inv);
        *(ushort4*)&ob[(size_t)qg * (NH * HD) + h * HD + dt * 16 + lk * 4] = o;
    }
}

extern "C" void kernel_launch(void* const* d_in, const int* in_sizes, int n_in,
                              void* d_out, int out_size, void* d_ws, size_t ws_size,
                              hipStream_t stream)
{
    const float* hs       = (const float*)d_in[0];
    const int*   pos      = (const int*)d_in[1];
    const int*   cu       = (const int*)d_in[2];
    const float* inv_freq = (const float*)d_in[3];
    const float* Wq       = (const float*)d_in[4];
    const float* bq       = (const float*)d_in[5];
    const float* Wk       = (const float*)d_in[6];
    const float* bk       = (const float*)d_in[7];
    const float* Wv       = (const float*)d_in[8];
    const float* bv       = (const float*)d_in[9];
    const float* Wo       = (const float*)d_in[10];
    float* out = (float*)d_out;

    unsigned short* hsb   = (unsigned short*)d_ws;          //  8,388,608
    unsigned short* wqkvT = hsb + 8388608;                  //  5,242,880
    unsigned short* wot   = wqkvT + 5242880;                //  4,194,304
    unsigned short* qkvb  = wot + 4194304;                  // 10,485,760
    unsigned short* vtb   = qkvb + 10485760;                //  1,048,576
    unsigned short* obb   = vtb + 1048576;                  //  8,388,608
    float* bqkv = (float*)(obb + 8388608);                  //  2,560 floats

    conv_bf16<<<8192, 256, 0, stream>>>(hs, hsb, T_TOK * HIDDEN);
    transpose_all<<<dim3((QKV_N + HIDDEN) / 32, HIDDEN / 32), 256, 0, stream>>>(
        Wq, Wk, Wv, Wo, wqkvT, wot);
    pack_bias<<<10, 256, 0, stream>>>(bq, bk, bv, bqkv);

    gemm8<0><<<dim3((T_TOK / 256) * (QKV_N / 256)), 512, 0, stream>>>(
        hsb, wqkvT, bqkv, qkvb, vtb, QKV_N, HIDDEN);

    rope_k<<<dim3(T_TOK / 2), 256, 0, stream>>>(qkvb, pos, inv_freq);

    attn_mfma<<<dim3(64 * NH), 256, 0, stream>>>(qkvb, vtb, cu, pos, inv_freq, obb);

    gemm8<1><<<dim3((T_TOK / 256) * (HIDDEN / 128)), 512, 0, stream>>>(
        obb, wot, nullptr, out, nullptr, HIDDEN, NH * HD);
}

// Round 10
// 213.951 us; speedup vs baseline: 1.2038x; 1.0671x over previous
//
#include <hip/hip_runtime.h>
#include <math.h>

#define T_TOK 4096
#define HIDDEN 2048
#define NH 16
#define NKVH 2
#define HD 128
#define NSEG 8
#define QKV_N 2560   // 2048 q + 256 k + 256 v
#define ROW_Q 0
#define ROW_K 2048
#define ROW_V 2304

typedef __attribute__((ext_vector_type(8))) short bf16x8;
typedef __attribute__((ext_vector_type(4))) float f32x4;

__device__ __forceinline__ unsigned short f2bf(float f) {
    union { float f; unsigned u; } x; x.f = f;
    unsigned r = x.u + 0x7FFF + ((x.u >> 16) & 1);
    return (unsigned short)(r >> 16);
}
__device__ __forceinline__ float bf2f(unsigned short u) {
    union { unsigned u; float f; } x; x.u = ((unsigned)u) << 16;
    return x.f;
}
__device__ __forceinline__ void gload16(const void* g, void* l) {
    __builtin_amdgcn_global_load_lds(
        (const __attribute__((address_space(1))) unsigned int*)g,
        (__attribute__((address_space(3))) unsigned int*)l, 16, 0, 0);
}

// Raw barrier: memory clobber orders LDS/VMEM ops; register-only MFMA may
// interleave with neighboring phases. vmcnt(N) is per-wave, so every counted
// wait sits immediately before a barrier (R7 lesson).
#define BAR() asm volatile("s_barrier" ::: "memory")

// ---------- merged prep: conv hs->bf16 | transpose Wq|Wk|Wv|Wo | pack bias ----
// grid = 8192 (conv) + 9216 (transpose 144x64) + 10 (bias) = 17418 blocks x 256
__global__ void prep_all(const float* __restrict__ hs, unsigned short* __restrict__ hsb,
                         const float* __restrict__ Wq, const float* __restrict__ Wk,
                         const float* __restrict__ Wv, const float* __restrict__ Wo,
                         unsigned short* __restrict__ wqkvT, unsigned short* __restrict__ wot,
                         const float* __restrict__ bq, const float* __restrict__ bk,
                         const float* __restrict__ bv, float* __restrict__ bqkv)
{
    const int bid = blockIdx.x;
    if (bid < 8192) {
        int i = (bid * 256 + threadIdx.x) * 4;
        float4 v = *(const float4*)&hs[i];
        ushort4 o;
        o.x = f2bf(v.x); o.y = f2bf(v.y); o.z = f2bf(v.z); o.w = f2bf(v.w);
        *(ushort4*)&hsb[i] = o;
    } else if (bid < 8192 + 9216) {
        __shared__ float tile[32][33];
        const int b2 = bid - 8192;
        const int n0 = (b2 % 144) * 32, k0 = (b2 / 144) * 32;
        const float* src; int col0, stride; unsigned short* dst; int dn0;
        if (n0 < ROW_K)       { src = Wq; col0 = n0;          stride = NH * HD;   dst = wqkvT; dn0 = n0; }
        else if (n0 < ROW_V)  { src = Wk; col0 = n0 - ROW_K;  stride = NKVH * HD; dst = wqkvT; dn0 = n0; }
        else if (n0 < QKV_N)  { src = Wv; col0 = n0 - ROW_V;  stride = NKVH * HD; dst = wqkvT; dn0 = n0; }
        else                  { src = Wo; col0 = n0 - QKV_N;  stride = HIDDEN;    dst = wot;   dn0 = n0 - QKV_N; }
        const int c = threadIdx.x & 31, r0 = threadIdx.x >> 5;
        #pragma unroll
        for (int r = r0; r < 32; r += 8)
            tile[r][c] = src[(size_t)(k0 + r) * stride + col0 + c];
        __syncthreads();
        #pragma unroll
        for (int r = r0; r < 32; r += 8)
            dst[(size_t)(dn0 + r) * HIDDEN + k0 + c] = f2bf(tile[c][r]);
    } else {
        int i = (bid - 8192 - 9216) * 256 + threadIdx.x;
        if (i < ROW_K) bqkv[i] = bq[i];
        else if (i < ROW_V) bqkv[i] = bk[i - ROW_K];
        else if (i < QKV_N) bqkv[i] = bv[i - ROW_V];
    }
}

// ---------- RoPE on packed qkv (q scaled by 1/sqrt(D)), fp32 math ----------
__global__ void rope_kernel(unsigned short* __restrict__ qkv, const int* __restrict__ pos,
                            const float* __restrict__ invf)
{
    const int tok = blockIdx.x * 4 + (threadIdx.x >> 6);
    const int f = threadIdx.x & 63;
    const float p = (float)pos[tok];
    const float ang = p * invf[f];
    const float c = cosf(ang), s = sinf(ang);
    const float SC = 0.08838834764831845f;
    unsigned short* row = qkv + (size_t)tok * QKV_N;
    #pragma unroll
    for (int h = 0; h < NH; ++h) {
        unsigned short* u = row + h * HD;
        const float x1 = bf2f(u[f]), x2 = bf2f(u[f + 64]);
        u[f]      = f2bf((x1 * c - x2 * s) * SC);
        u[f + 64] = f2bf((x2 * c + x1 * s) * SC);
    }
    #pragma unroll
    for (int h = 0; h < NKVH; ++h) {
        unsigned short* u = row + ROW_K + h * HD;
        const float x1 = bf2f(u[f]), x2 = bf2f(u[f + 64]);
        u[f]      = f2bf(x1 * c - x2 * s);
        u[f + 64] = f2bf(x2 * c + x1 * s);
    }
}

// ============ 8-phase 256xBN MFMA GEMM (T3+T4+T5) — R6-proven skeleton ========
// NEW: 2D XCD chunking (each XCD owns a 4x(5|8) tile chunk -> B panels L2-resident).
// MODE 0: BN=256, tiles 16x10, chunk 4x5, bf16 out + bias, V transposed to vt
// MODE 1: BN=128, tiles 16x16, chunk 4x8, f32 out
template<int MODE>
__global__ __launch_bounds__(512, 2) void gemm8(const unsigned short* __restrict__ A,
                                                const unsigned short* __restrict__ BT,
                                                const float* __restrict__ bias,
                                                void* __restrict__ Cout,
                                                unsigned short* __restrict__ vt,
                                                int N, int K)
{
    constexpr int BN    = (MODE == 0) ? 256 : 128;
    constexpr int NPH   = (MODE == 0) ? 2 : 1;
    constexpr int BHALF = (MODE == 0) ? 16384 : 8192;
    constexpr int ABUF  = 32768;
    constexpr int BBUF  = 2 * BHALF;
    constexpr int BOFF  = 2 * ABUF;
    __shared__ __align__(16) unsigned char lds[BOFF + 2 * BBUF];

    const int tid = threadIdx.x, lane = tid & 63, w = tid >> 6;
    const int wm = w >> 2, wn = w & 3;
    const int lr = lane & 15, lk = lane >> 4;

    // 2D XCD chunk swizzle: xcd = bid&7 owns chunk (xcd>>1, xcd&1) of CRxCC tiles
    const int bid = blockIdx.x;
    const int xcd = bid & 7, idx = bid >> 3;
    int brow, bcol;
    if constexpr (MODE == 0) {            // 16 x 10 tiles, chunk 4x5
        const int tr = idx / 5, tc = idx % 5;
        brow = ((xcd >> 1) * 4 + tr) * 256;
        bcol = ((xcd & 1) * 5 + tc) * BN;
    } else {                              // 16 x 16 tiles, chunk 4x8
        const int tr = idx >> 3, tc = idx & 7;
        brow = ((xcd >> 1) * 4 + tr) * 256;
        bcol = ((xcd & 1) * 8 + tc) * BN;
    }

    const size_t aRow = (size_t)(brow + w * 16 + lr) * K + lk * 8;
    size_t bRow;
    if constexpr (MODE == 0) bRow = (size_t)(bcol + w * 16 + lr) * K + lk * 8;
    else                     bRow = (size_t)(bcol + (w >> 1) * 16 + lr) * K + ((w & 1) * 4 + lk) * 8;
    const int dstA = w * 2048 + lane * 16;
    const int dstB = (MODE == 0) ? dstA : (w * 1024 + lane * 16);

    auto stA = [&](int kt, int h, int b) {
        const unsigned short* s = A + aRow + (size_t)h * 128 * K + kt * 64;
        unsigned char* d = lds + b * ABUF + h * 16384 + dstA;
        gload16(s, d);
        gload16(s + 32, d + 1024);
    };
    auto stB = [&](int kt, int h, int b) {
        const unsigned short* s = BT + bRow + (size_t)h * (BN / 2) * K + kt * 64;
        unsigned char* d = lds + BOFF + b * BBUF + h * BHALF + dstB;
        gload16(s, d);
        if constexpr (MODE == 0) gload16(s + 32, d + 1024);
    };

    const int fragOff = lk * 256 + lr * 16;
    auto ldA = [&](int b, int mh, int m, int kk) -> bf16x8 {
        return *(const bf16x8*)(lds + b * ABUF + mh * 16384 + (wm * 4 + m) * 2048
                                + kk * 1024 + fragOff);
    };
    auto ldB = [&](int b, int nh, int n, int kk) -> bf16x8 {
        const int sub = (MODE == 0) ? (wn * 2 + n) : wn;
        return *(const bf16x8*)(lds + BOFF + b * BBUF + nh * BHALF + sub * 2048
                                + kk * 1024 + fragOff);
    };

    f32x4 acc[8][2 * NPH];
    #pragma unroll
    for (int i = 0; i < 8; ++i)
        #pragma unroll
        for (int j = 0; j < 2 * NPH; ++j)
            acc[i][j] = f32x4{0.f, 0.f, 0.f, 0.f};

    const int NT = K >> 6;

    stA(0, 0, 0); stA(0, 1, 0); stB(0, 0, 0); stB(0, 1, 0);
    stA(1, 0, 1); stB(1, 0, 1); stB(1, 1, 1);
    if constexpr (MODE == 0) asm volatile("s_waitcnt vmcnt(6)" ::: "memory");
    else                     asm volatile("s_waitcnt vmcnt(4)" ::: "memory");
    BAR();

    for (int kt = 0; kt < NT; ++kt) {
        const int b = kt & 1;
        bf16x8 af[4][2], bfr[2][NPH][2];

        // ---- ph0: read A-h0 + B-h0; stage A1(kt+1) -> buf b^1
        #pragma unroll
        for (int m = 0; m < 4; ++m) {
            af[m][0] = ldA(b, 0, m, 0);
            af[m][1] = ldA(b, 0, m, 1);
        }
        #pragma unroll
        for (int n = 0; n < NPH; ++n) {
            bfr[0][n][0] = ldB(b, 0, n, 0);
            bfr[0][n][1] = ldB(b, 0, n, 1);
        }
        if (kt + 1 < NT) stA(kt + 1, 1, b ^ 1);
        BAR();
        __builtin_amdgcn_s_setprio(1);
        #pragma unroll
        for (int m = 0; m < 4; ++m)
            #pragma unroll
            for (int n = 0; n < NPH; ++n)
                #pragma unroll
                for (int kk = 0; kk < 2; ++kk)
                    acc[m][n] = __builtin_amdgcn_mfma_f32_16x16x32_bf16(
                        af[m][kk], bfr[0][n][kk], acc[m][n], 0, 0, 0);
        __builtin_amdgcn_s_setprio(0);
        BAR();

        // ---- ph1: read B-h1; stage A0(kt+2) -> buf b
        #pragma unroll
        for (int n = 0; n < NPH; ++n) {
            bfr[1][n][0] = ldB(b, 1, n, 0);
            bfr[1][n][1] = ldB(b, 1, n, 1);
        }
        if (kt + 2 < NT) stA(kt + 2, 0, b);
        BAR();
        __builtin_amdgcn_s_setprio(1);
        #pragma unroll
        for (int m = 0; m < 4; ++m)
            #pragma unroll
            for (int n = 0; n < NPH; ++n)
                #pragma unroll
                for (int kk = 0; kk < 2; ++kk)
                    acc[m][NPH + n] = __builtin_amdgcn_mfma_f32_16x16x32_bf16(
                        af[m][kk], bfr[1][n][kk], acc[m][NPH + n], 0, 0, 0);
        __builtin_amdgcn_s_setprio(0);
        BAR();

        // ---- ph2: read A-h1; stage B0(kt+2) -> buf b
        #pragma unroll
        for (int m = 0; m < 4; ++m) {
            af[m][0] = ldA(b, 1, m, 0);
            af[m][1] = ldA(b, 1, m, 1);
        }
        if (kt + 2 < NT) stB(kt + 2, 0, b);
        BAR();
        __builtin_amdgcn_s_setprio(1);
        #pragma unroll
        for (int m = 0; m < 4; ++m)
            #pragma unroll
            for (int n = 0; n < NPH; ++n)
                #pragma unroll
                for (int kk = 0; kk < 2; ++kk)
                    acc[4 + m][n] = __builtin_amdgcn_mfma_f32_16x16x32_bf16(
                        af[m][kk], bfr[0][n][kk], acc[4 + m][n], 0, 0, 0);
        __builtin_amdgcn_s_setprio(0);
        BAR();

        // ---- ph3: stage B1(kt+2) -> buf b; counted vmcnt just before barrier
        if (kt + 2 < NT) stB(kt + 2, 1, b);
        if (kt < NT - 2) {
            if constexpr (MODE == 0) asm volatile("s_waitcnt vmcnt(6)" ::: "memory");
            else                     asm volatile("s_waitcnt vmcnt(4)" ::: "memory");
        } else {
            asm volatile("s_waitcnt vmcnt(0)" ::: "memory");
        }
        BAR();
        __builtin_amdgcn_s_setprio(1);
        #pragma unroll
        for (int m = 0; m < 4; ++m)
            #pragma unroll
            for (int n = 0; n < NPH; ++n)
                #pragma unroll
                for (int kk = 0; kk < 2; ++kk)
                    acc[4 + m][NPH + n] = __builtin_amdgcn_mfma_f32_16x16x32_bf16(
                        af[m][kk], bfr[1][n][kk], acc[4 + m][NPH + n], 0, 0, 0);
        __builtin_amdgcn_s_setprio(0);
        BAR();
    }

    #pragma unroll
    for (int ms = 0; ms < 8; ++ms) {
        const int row = brow + (ms >> 2) * 128 + wm * 64 + (ms & 3) * 16 + lk * 4;
        #pragma unroll
        for (int ns = 0; ns < 2 * NPH; ++ns) {
            int col;
            if constexpr (MODE == 0)
                col = bcol + (ns >> 1) * 128 + wn * 32 + (ns & 1) * 16 + lr;
            else
                col = bcol + ns * 64 + wn * 16 + lr;
            const float bbv = (MODE == 0) ? bias[col] : 0.f;
            if (MODE == 0 && col >= ROW_V) {
                ushort4 o;
                o.x = f2bf(acc[ms][ns][0] + bbv);
                o.y = f2bf(acc[ms][ns][1] + bbv);
                o.z = f2bf(acc[ms][ns][2] + bbv);
                o.w = f2bf(acc[ms][ns][3] + bbv);
                *(ushort4*)&vt[(size_t)(col - ROW_V) * T_TOK + row] = o;
            } else {
                #pragma unroll
                for (int j = 0; j < 4; ++j) {
                    const float vv = acc[ms][ns][j] + bbv;
                    if (MODE == 0)
                        ((unsigned short*)Cout)[(size_t)(row + j) * QKV_N + col] = f2bf(vv);
                    else
                        ((float*)Cout)[(size_t)(row + j) * HIDDEN + col] = vv;
                }
            }
        }
    }
}

// ---------- varlen causal GQA flash attention (R6-proven) ----------
// Swapped-operand MFMA: S^T = mfma(K,Q), O^T = mfma(V^T, P^T). P in registers.
__global__ __launch_bounds__(256) void attn_mfma(const unsigned short* __restrict__ qkv,
                                                 const unsigned short* __restrict__ vt,
                                                 const int* __restrict__ cu,
                                                 unsigned short* __restrict__ ob)
{
    __shared__ __align__(16) unsigned short Klds[2][4096]; // [st2][kk4][lk4][lr16][8]
    __shared__ __align__(16) unsigned short Vlds[2][4096]; // [dt8][lk4][lr16][8]

    const int tid = threadIdx.x;
    const int l = tid & 63, w = tid >> 6;
    const int lr = l & 15, lk = l >> 4;

    const int bid = blockIdx.x;
    const int h = bid >> 6;
    const int qb = (bid + 37 * (bid >> 6)) & 63;   // balance swizzle
    const int q0 = qb * 64;
    const int kvh = h >> 3;

    bf16x8 aq[4];
    #pragma unroll
    for (int kk = 0; kk < 4; ++kk)
        aq[kk] = *(const bf16x8*)&qkv[(size_t)(q0 + w * 16 + lr) * QKV_N + h * HD + kk * 32 + lk * 8];

    const int qg = q0 + w * 16 + lr;
    int seg_lo = 0, seg_last = 0, sb = 0;
    #pragma unroll
    for (int x = 1; x < NSEG; ++x) {
        const int cx = cu[x];
        seg_lo   = (cx <= qg)      ? cx : seg_lo;
        seg_last = (cx <= q0 + 63) ? cx : seg_last;
        sb       = (cx <= q0)      ? cx : sb;
    }
    sb &= ~31;

    const int lr_s = tid & 15, lk_s = (tid >> 4) & 3, w_s = tid >> 6;
    const unsigned short* kSrc0 = qkv + (size_t)(sb + lr_s) * QKV_N + ROW_K + kvh * HD + w_s * 32 + lk_s * 8;
    const unsigned short* kSrc1 = kSrc0 + (size_t)16 * QKV_N;
    const unsigned short* vSrc0 = vt + (size_t)(kvh * HD + w_s * 16 + lr_s) * T_TOK + sb + lk_s * 8;
    const unsigned short* vSrc1 = vSrc0 + (size_t)64 * T_TOK;

    float m_r = -1e30f, l_r = 0.f;
    f32x4 oacc[8];
    #pragma unroll
    for (int d = 0; d < 8; ++d) oacc[d] = f32x4{0.f, 0.f, 0.f, 0.f};

    const int nt = ((q0 + 63 - sb) >> 5) + 1;

    gload16(kSrc0, &Klds[0][tid * 8]);
    gload16(kSrc1, &Klds[0][2048 + tid * 8]);
    gload16(vSrc0, &Vlds[0][tid * 8]);
    gload16(vSrc1, &Vlds[0][2048 + tid * 8]);
    __syncthreads();

    int buf = 0;
    for (int t = 0; t < nt; ++t) {
        const int s0 = sb + t * 32;
        kSrc0 += 32 * QKV_N; kSrc1 += 32 * QKV_N;
        vSrc0 += 32;         vSrc1 += 32;
        if (t + 1 < nt) {
            gload16(kSrc0, &Klds[buf ^ 1][tid * 8]);
            gload16(kSrc1, &Klds[buf ^ 1][2048 + tid * 8]);
            gload16(vSrc0, &Vlds[buf ^ 1][tid * 8]);
            gload16(vSrc1, &Vlds[buf ^ 1][2048 + tid * 8]);
        }

        f32x4 sacc[2];
        sacc[0] = f32x4{0.f, 0.f, 0.f, 0.f};
        sacc[1] = f32x4{0.f, 0.f, 0.f, 0.f};
        #pragma unroll
        for (int kk = 0; kk < 4; ++kk) {
            bf16x8 ak0 = *(const bf16x8*)&Klds[buf][kk * 512 + lk * 128 + lr * 8];
            bf16x8 ak1 = *(const bf16x8*)&Klds[buf][2048 + kk * 512 + lk * 128 + lr * 8];
            sacc[0] = __builtin_amdgcn_mfma_f32_16x16x32_bf16(ak0, aq[kk], sacc[0], 0, 0, 0);
            sacc[1] = __builtin_amdgcn_mfma_f32_16x16x32_bf16(ak1, aq[kk], sacc[1], 0, 0, 0);
        }

        float x[8];
        #pragma unroll
        for (int st = 0; st < 2; ++st)
            #pragma unroll
            for (int jj = 0; jj < 4; ++jj)
                x[st * 4 + jj] = sacc[st][jj];

        const bool fast = (s0 >= seg_last) && (s0 + 31 <= q0);
        if (!fast) {
            #pragma unroll
            for (int st = 0; st < 2; ++st)
                #pragma unroll
                for (int jj = 0; jj < 4; ++jj) {
                    const int sg = s0 + st * 16 + lk * 4 + jj;
                    const bool vld = (sg >= seg_lo) && (sg <= qg);
                    x[st * 4 + jj] = vld ? x[st * 4 + jj] : -3e38f;
                }
        }

        float mx = fmaxf(fmaxf(fmaxf(x[0], x[1]), fmaxf(x[2], x[3])),
                         fmaxf(fmaxf(x[4], x[5]), fmaxf(x[6], x[7])));
        mx = fmaxf(mx, __shfl_xor(mx, 16));
        mx = fmaxf(mx, __shfl_xor(mx, 32));
        const float mn = fmaxf(m_r, mx);
        const float al = __expf(m_r - mn);
        float p[8], ps = 0.f;
        #pragma unroll
        for (int i = 0; i < 8; ++i) { p[i] = __expf(x[i] - mn); ps += p[i]; }
        ps += __shfl_xor(ps, 16);
        ps += __shfl_xor(ps, 32);
        l_r = l_r * al + ps;
        m_r = mn;

        #pragma unroll
        for (int dt = 0; dt < 8; ++dt) {
            oacc[dt][0] *= al; oacc[dt][1] *= al;
            oacc[dt][2] *= al; oacc[dt][3] *= al;
        }

        int u00 = ((int)f2bf(p[1]) << 16) | f2bf(p[0]);
        int u01 = ((int)f2bf(p[3]) << 16) | f2bf(p[2]);
        int u10 = ((int)f2bf(p[5]) << 16) | f2bf(p[4]);
        int u11 = ((int)f2bf(p[7]) << 16) | f2bf(p[6]);

        const int srcA = (lk & 1) * 32 + lr;
        const int srcB = srcA + 16;
        const bool hi = (lk & 2) != 0;
        int a0 = __shfl(u00, srcA), b0 = __shfl(u10, srcA);
        int a1 = __shfl(u01, srcA), b1 = __shfl(u11, srcA);
        int a2 = __shfl(u00, srcB), b2 = __shfl(u10, srcB);
        int a3 = __shfl(u01, srcB), b3 = __shfl(u11, srcB);
        union { int wds[4]; bf16x8 v; } pf;
        pf.wds[0] = hi ? b0 : a0;
        pf.wds[1] = hi ? b1 : a1;
        pf.wds[2] = hi ? b2 : a2;
        pf.wds[3] = hi ? b3 : a3;

        #pragma unroll
        for (int dt = 0; dt < 8; ++dt) {
            bf16x8 av = *(const bf16x8*)&Vlds[buf][dt * 512 + lk * 128 + lr * 8];
            oacc[dt] = __builtin_amdgcn_mfma_f32_16x16x32_bf16(av, pf.v, oacc[dt], 0, 0, 0);
        }
        __syncthreads();
        buf ^= 1;
    }

    const float inv = 1.f / l_r;
    #pragma unroll
    for (int dt = 0; dt < 8; ++dt) {
        ushort4 o;
        o.x = f2bf(oacc[dt][0] * inv);
        o.y = f2bf(oacc[dt][1] * inv);
        o.z = f2bf(oacc[dt][2] * inv);
        o.w = f2bf(oacc[dt][3] * inv);
        *(ushort4*)&ob[(size_t)qg * (NH * HD) + h * HD + dt * 16 + lk * 4] = o;
    }
}

extern "C" void kernel_launch(void* const* d_in, const int* in_sizes, int n_in,
                              void* d_out, int out_size, void* d_ws, size_t ws_size,
                              hipStream_t stream)
{
    const float* hs       = (const float*)d_in[0];
    const int*   pos      = (const int*)d_in[1];
    const int*   cu       = (const int*)d_in[2];
    const float* inv_freq = (const float*)d_in[3];
    const float* Wq       = (const float*)d_in[4];
    const float* bq       = (const float*)d_in[5];
    const float* Wk       = (const float*)d_in[6];
    const float* bk       = (const float*)d_in[7];
    const float* Wv       = (const float*)d_in[8];
    const float* bv       = (const float*)d_in[9];
    const float* Wo       = (const float*)d_in[10];
    float* out = (float*)d_out;

    unsigned short* hsb   = (unsigned short*)d_ws;          //  8,388,608
    unsigned short* wqkvT = hsb + 8388608;                  //  5,242,880
    unsigned short* wot   = wqkvT + 5242880;                //  4,194,304
    unsigned short* qkvb  = wot + 4194304;                  // 10,485,760
    unsigned short* vtb   = qkvb + 10485760;                //  1,048,576
    unsigned short* obb   = vtb + 1048576;                  //  8,388,608
    float* bqkv = (float*)(obb + 8388608);                  //  2,560 floats

    prep_all<<<dim3(8192 + 9216 + 10), 256, 0, stream>>>(
        hs, hsb, Wq, Wk, Wv, Wo, wqkvT, wot, bq, bk, bv, bqkv);

    gemm8<0><<<dim3((T_TOK / 256) * (QKV_N / 256)), 512, 0, stream>>>(
        hsb, wqkvT, bqkv, qkvb, vtb, QKV_N, HIDDEN);

    rope_kernel<<<dim3(T_TOK / 4), 256, 0, stream>>>(qkvb, pos, inv_freq);

    attn_mfma<<<dim3(64 * NH), 256, 0, stream>>>(qkvb, vtb, cu, obb);

    gemm8<1><<<dim3((T_TOK / 256) * (HIDDEN / 128)), 512, 0, stream>>>(
        obb, wot, nullptr, out, nullptr, HIDDEN, NH * HD);
}

// Round 12
// 213.394 us; speedup vs baseline: 1.2069x; 1.0026x over previous
//
#include <hip/hip_runtime.h>
#include <math.h>

#define T_TOK 4096
#define HIDDEN 2048
#define NH 16
#define NKVH 2
#define HD 128
#define NSEG 8
#define QKV_N 2560   // 2048 q + 256 k + 256 v
#define ROW_Q 0
#define ROW_K 2048
#define ROW_V 2304

typedef __attribute__((ext_vector_type(8))) short bf16x8;
typedef __attribute__((ext_vector_type(4))) float f32x4;

__device__ __forceinline__ unsigned short f2bf(float f) {
    union { float f; unsigned u; } x; x.f = f;
    unsigned r = x.u + 0x7FFF + ((x.u >> 16) & 1);
    return (unsigned short)(r >> 16);
}
__device__ __forceinline__ float bf2f(unsigned short u) {
    union { unsigned u; float f; } x; x.u = ((unsigned)u) << 16;
    return x.f;
}
__device__ __forceinline__ void gload16(const void* g, void* l) {
    __builtin_amdgcn_global_load_lds(
        (const __attribute__((address_space(1))) unsigned int*)g,
        (__attribute__((address_space(3))) unsigned int*)l, 16, 0, 0);
}

// Raw barrier: memory clobber orders LDS/VMEM ops; register-only MFMA may
// interleave with neighboring phases. vmcnt(N) is per-wave, so every counted
// wait sits immediately before a barrier (R7 lesson).
#define BAR() asm volatile("s_barrier" ::: "memory")

// ---------- merged prep: conv hs->bf16 | transpose Wq|Wk|Wv|Wo | pack bias ----
__global__ void prep_all(const float* __restrict__ hs, unsigned short* __restrict__ hsb,
                         const float* __restrict__ Wq, const float* __restrict__ Wk,
                         const float* __restrict__ Wv, const float* __restrict__ Wo,
                         unsigned short* __restrict__ wqkvT, unsigned short* __restrict__ wot,
                         const float* __restrict__ bq, const float* __restrict__ bk,
                         const float* __restrict__ bv, float* __restrict__ bqkv)
{
    const int bid = blockIdx.x;
    if (bid < 8192) {
        int i = (bid * 256 + threadIdx.x) * 4;
        float4 v = *(const float4*)&hs[i];
        ushort4 o;
        o.x = f2bf(v.x); o.y = f2bf(v.y); o.z = f2bf(v.z); o.w = f2bf(v.w);
        *(ushort4*)&hsb[i] = o;
    } else if (bid < 8192 + 9216) {
        __shared__ float tile[32][33];
        const int b2 = bid - 8192;
        const int n0 = (b2 % 144) * 32, k0 = (b2 / 144) * 32;
        const float* src; int col0, stride; unsigned short* dst; int dn0;
        if (n0 < ROW_K)       { src = Wq; col0 = n0;          stride = NH * HD;   dst = wqkvT; dn0 = n0; }
        else if (n0 < ROW_V)  { src = Wk; col0 = n0 - ROW_K;  stride = NKVH * HD; dst = wqkvT; dn0 = n0; }
        else if (n0 < QKV_N)  { src = Wv; col0 = n0 - ROW_V;  stride = NKVH * HD; dst = wqkvT; dn0 = n0; }
        else                  { src = Wo; col0 = n0 - QKV_N;  stride = HIDDEN;    dst = wot;   dn0 = n0 - QKV_N; }
        const int c = threadIdx.x & 31, r0 = threadIdx.x >> 5;
        #pragma unroll
        for (int r = r0; r < 32; r += 8)
            tile[r][c] = src[(size_t)(k0 + r) * stride + col0 + c];
        __syncthreads();
        #pragma unroll
        for (int r = r0; r < 32; r += 8)
            dst[(size_t)(dn0 + r) * HIDDEN + k0 + c] = f2bf(tile[c][r]);
    } else {
        int i = (bid - 8192 - 9216) * 256 + threadIdx.x;
        if (i < ROW_K) bqkv[i] = bq[i];
        else if (i < ROW_V) bqkv[i] = bk[i - ROW_K];
        else if (i < QKV_N) bqkv[i] = bv[i - ROW_V];
    }
}

// ---------- RoPE on packed qkv (q scaled by 1/sqrt(D)), fp32 math ----------
__global__ void rope_kernel(unsigned short* __restrict__ qkv, const int* __restrict__ pos,
                            const float* __restrict__ invf)
{
    const int tok = blockIdx.x * 4 + (threadIdx.x >> 6);
    const int f = threadIdx.x & 63;
    const float p = (float)pos[tok];
    const float ang = p * invf[f];
    const float c = cosf(ang), s = sinf(ang);
    const float SC = 0.08838834764831845f;
    unsigned short* row = qkv + (size_t)tok * QKV_N;
    #pragma unroll
    for (int h = 0; h < NH; ++h) {
        unsigned short* u = row + h * HD;
        const float x1 = bf2f(u[f]), x2 = bf2f(u[f + 64]);
        u[f]      = f2bf((x1 * c - x2 * s) * SC);
        u[f + 64] = f2bf((x2 * c + x1 * s) * SC);
    }
    #pragma unroll
    for (int h = 0; h < NKVH; ++h) {
        unsigned short* u = row + ROW_K + h * HD;
        const float x1 = bf2f(u[f]), x2 = bf2f(u[f + 64]);
        u[f]      = f2bf(x1 * c - x2 * s);
        u[f + 64] = f2bf(x2 * c + x1 * s);
    }
}

// ============ 8-phase 256xBN MFMA GEMM — 2-K-tile unrolled, branch-free body ==
// MODE 0: BN=256, tiles 16x10, chunk 4x5, bf16 out + bias, V transposed to vt
// MODE 1: BN=128, tiles 16x16, chunk 4x8, f32 out
template<int MODE>
__global__ __launch_bounds__(512, 2) void gemm8(const unsigned short* __restrict__ A,
                                                const unsigned short* __restrict__ BT,
                                                const float* __restrict__ bias,
                                                void* __restrict__ Cout,
                                                unsigned short* __restrict__ vt,
                                                int N, int K)
{
    constexpr int BN    = (MODE == 0) ? 256 : 128;
    constexpr int NPH   = (MODE == 0) ? 2 : 1;
    constexpr int BHALF = (MODE == 0) ? 16384 : 8192;
    constexpr int ABUF  = 32768;
    constexpr int BBUF  = 2 * BHALF;
    constexpr int BOFF  = 2 * ABUF;
    __shared__ __align__(16) unsigned char lds[BOFF + 2 * BBUF];

    const int tid = threadIdx.x, lane = tid & 63, w = tid >> 6;
    const int wm = w >> 2, wn = w & 3;
    const int lr = lane & 15, lk = lane >> 4;

    // 2D XCD chunk swizzle
    const int bid = blockIdx.x;
    const int xcd = bid & 7, idx = bid >> 3;
    int brow, bcol;
    if constexpr (MODE == 0) {
        const int tr = idx / 5, tc = idx % 5;
        brow = ((xcd >> 1) * 4 + tr) * 256;
        bcol = ((xcd & 1) * 5 + tc) * BN;
    } else {
        const int tr = idx >> 3, tc = idx & 7;
        brow = ((xcd >> 1) * 4 + tr) * 256;
        bcol = ((xcd & 1) * 8 + tc) * BN;
    }

    const size_t aRow = (size_t)(brow + w * 16 + lr) * K + lk * 8;
    size_t bRow;
    if constexpr (MODE == 0) bRow = (size_t)(bcol + w * 16 + lr) * K + lk * 8;
    else                     bRow = (size_t)(bcol + (w >> 1) * 16 + lr) * K + ((w & 1) * 4 + lk) * 8;
    const int dstA = w * 2048 + lane * 16;
    const int dstB = (MODE == 0) ? dstA : (w * 1024 + lane * 16);

    auto stA = [&](int kt, int h, int b) {
        const unsigned short* s = A + aRow + (size_t)h * 128 * K + kt * 64;
        unsigned char* d = lds + b * ABUF + h * 16384 + dstA;
        gload16(s, d);
        gload16(s + 32, d + 1024);
    };
    auto stB = [&](int kt, int h, int b) {
        const unsigned short* s = BT + bRow + (size_t)h * (BN / 2) * K + kt * 64;
        unsigned char* d = lds + BOFF + b * BBUF + h * BHALF + dstB;
        gload16(s, d);
        if constexpr (MODE == 0) gload16(s + 32, d + 1024);
    };

    const int fragOff = lk * 256 + lr * 16;
    auto ldA = [&](int b, int mh, int m, int kk) -> bf16x8 {
        return *(const bf16x8*)(lds + b * ABUF + mh * 16384 + (wm * 4 + m) * 2048
                                + kk * 1024 + fragOff);
    };
    auto ldB = [&](int b, int nh, int n, int kk) -> bf16x8 {
        const int sub = (MODE == 0) ? (wn * 2 + n) : wn;
        return *(const bf16x8*)(lds + BOFF + b * BBUF + nh * BHALF + sub * 2048
                                + kk * 1024 + fragOff);
    };

    f32x4 acc[8][2 * NPH];
    #pragma unroll
    for (int i = 0; i < 8; ++i)
        #pragma unroll
        for (int j = 0; j < 2 * NPH; ++j)
            acc[i][j] = f32x4{0.f, 0.f, 0.f, 0.f};

    const int NT = K >> 6;
    bf16x8 af[4][2], bfr[2][NPH][2];

#define RD_A(b_, mh_)  { _Pragma("unroll") for (int m = 0; m < 4; ++m) { \
        af[m][0] = ldA(b_, mh_, m, 0); af[m][1] = ldA(b_, mh_, m, 1); } }
#define RD_B(b_, nh_, dst_)  { _Pragma("unroll") for (int n = 0; n < NPH; ++n) { \
        bfr[dst_][n][0] = ldB(b_, nh_, n, 0); bfr[dst_][n][1] = ldB(b_, nh_, n, 1); } }
#define MM(mo_, no_)  { __builtin_amdgcn_s_setprio(1); \
    _Pragma("unroll") for (int m = 0; m < 4; ++m) \
        _Pragma("unroll") for (int n = 0; n < NPH; ++n) \
            _Pragma("unroll") for (int kk = 0; kk < 2; ++kk) \
                acc[(mo_) + m][(no_) + n] = __builtin_amdgcn_mfma_f32_16x16x32_bf16( \
                    af[m][kk], bfr[(no_) ? 1 : 0][n][kk], acc[(mo_) + m][(no_) + n], 0, 0, 0); \
    __builtin_amdgcn_s_setprio(0); }
#define VMC() { if constexpr (MODE == 0) asm volatile("s_waitcnt vmcnt(6)" ::: "memory"); \
                else                     asm volatile("s_waitcnt vmcnt(4)" ::: "memory"); }

// One K-tile, unconditional stages (caller bounds guarantee kt_+2 <= NT-1)
#define KTILE(kt_, b_) { \
    RD_A(b_, 0); RD_B(b_, 0, 0); stA((kt_) + 1, 1, (b_) ^ 1); \
    BAR(); MM(0, 0); BAR(); \
    RD_B(b_, 1, 1); stA((kt_) + 2, 0, b_); \
    BAR(); MM(0, NPH); BAR(); \
    RD_A(b_, 1); stB((kt_) + 2, 0, b_); \
    BAR(); MM(4, 0); BAR(); \
    stB((kt_) + 2, 1, b_); VMC(); \
    BAR(); MM(4, NPH); BAR(); }

// One K-tile, no stages, no barriers (epilogue: everything pre-staged)
#define KTILE_E(b_) { \
    RD_A(b_, 0); RD_B(b_, 0, 0); MM(0, 0); \
    RD_B(b_, 1, 1); MM(0, NPH); \
    RD_A(b_, 1); MM(4, 0); \
    MM(4, NPH); }

    // prologue: K0 fully + {A0,B0,B1} of K1
    stA(0, 0, 0); stA(0, 1, 0); stB(0, 0, 0); stB(0, 1, 0);
    stA(1, 0, 1); stB(1, 0, 1); stB(1, 1, 1);
    VMC();
    BAR();

    // main loop: 2 K-tiles per iteration, branch-free (tiles 0 .. NT-3)
    for (int kt = 0; kt + 3 < NT; kt += 2) {
        KTILE(kt, 0);
        KTILE(kt + 1, 1);
    }

    // R12 FIX: tile NT-1's A-h1 is staged by KTILE(NT-2) in the guarded loop,
    // but the branch-free loop ends at kt=NT-3 -> issue it here explicitly.
    // (WAR-safe: buf1 A-h1 last read in KTILE(NT-3,1) ph2, barrier-ordered.)
    stA(NT - 1, 1, 1);

    // peeled epilogue: tiles NT-2 (buf0), NT-1 (buf1) — now fully staged
    asm volatile("s_waitcnt vmcnt(0)" ::: "memory");
    BAR();
    KTILE_E(0);
    KTILE_E(1);

#undef RD_A
#undef RD_B
#undef MM
#undef VMC
#undef KTILE
#undef KTILE_E

    #pragma unroll
    for (int ms = 0; ms < 8; ++ms) {
        const int row = brow + (ms >> 2) * 128 + wm * 64 + (ms & 3) * 16 + lk * 4;
        #pragma unroll
        for (int ns = 0; ns < 2 * NPH; ++ns) {
            int col;
            if constexpr (MODE == 0)
                col = bcol + (ns >> 1) * 128 + wn * 32 + (ns & 1) * 16 + lr;
            else
                col = bcol + ns * 64 + wn * 16 + lr;
            const float bbv = (MODE == 0) ? bias[col] : 0.f;
            if (MODE == 0 && col >= ROW_V) {
                ushort4 o;
                o.x = f2bf(acc[ms][ns][0] + bbv);
                o.y = f2bf(acc[ms][ns][1] + bbv);
                o.z = f2bf(acc[ms][ns][2] + bbv);
                o.w = f2bf(acc[ms][ns][3] + bbv);
                *(ushort4*)&vt[(size_t)(col - ROW_V) * T_TOK + row] = o;
            } else {
                #pragma unroll
                for (int j = 0; j < 4; ++j) {
                    const float vv = acc[ms][ns][j] + bbv;
                    if (MODE == 0)
                        ((unsigned short*)Cout)[(size_t)(row + j) * QKV_N + col] = f2bf(vv);
                    else
                        ((float*)Cout)[(size_t)(row + j) * HIDDEN + col] = vv;
                }
            }
        }
    }
}

// ---------- varlen causal GQA flash attention (R6-proven) ----------
__global__ __launch_bounds__(256) void attn_mfma(const unsigned short* __restrict__ qkv,
                                                 const unsigned short* __restrict__ vt,
                                                 const int* __restrict__ cu,
                                                 unsigned short* __restrict__ ob)
{
    __shared__ __align__(16) unsigned short Klds[2][4096];
    __shared__ __align__(16) unsigned short Vlds[2][4096];

    const int tid = threadIdx.x;
    const int l = tid & 63, w = tid >> 6;
    const int lr = l & 15, lk = l >> 4;

    const int bid = blockIdx.x;
    const int h = bid >> 6;
    const int qb = (bid + 37 * (bid >> 6)) & 63;
    const int q0 = qb * 64;
    const int kvh = h >> 3;

    bf16x8 aq[4];
    #pragma unroll
    for (int kk = 0; kk < 4; ++kk)
        aq[kk] = *(const bf16x8*)&qkv[(size_t)(q0 + w * 16 + lr) * QKV_N + h * HD + kk * 32 + lk * 8];

    const int qg = q0 + w * 16 + lr;
    int seg_lo = 0, seg_last = 0, sb = 0;
    #pragma unroll
    for (int x = 1; x < NSEG; ++x) {
        const int cx = cu[x];
        seg_lo   = (cx <= qg)      ? cx : seg_lo;
        seg_last = (cx <= q0 + 63) ? cx : seg_last;
        sb       = (cx <= q0)      ? cx : sb;
    }
    sb &= ~31;

    const int lr_s = tid & 15, lk_s = (tid >> 4) & 3, w_s = tid >> 6;
    const unsigned short* kSrc0 = qkv + (size_t)(sb + lr_s) * QKV_N + ROW_K + kvh * HD + w_s * 32 + lk_s * 8;
    const unsigned short* kSrc1 = kSrc0 + (size_t)16 * QKV_N;
    const unsigned short* vSrc0 = vt + (size_t)(kvh * HD + w_s * 16 + lr_s) * T_TOK + sb + lk_s * 8;
    const unsigned short* vSrc1 = vSrc0 + (size_t)64 * T_TOK;

    float m_r = -1e30f, l_r = 0.f;
    f32x4 oacc[8];
    #pragma unroll
    for (int d = 0; d < 8; ++d) oacc[d] = f32x4{0.f, 0.f, 0.f, 0.f};

    const int nt = ((q0 + 63 - sb) >> 5) + 1;

    gload16(kSrc0, &Klds[0][tid * 8]);
    gload16(kSrc1, &Klds[0][2048 + tid * 8]);
    gload16(vSrc0, &Vlds[0][tid * 8]);
    gload16(vSrc1, &Vlds[0][2048 + tid * 8]);
    __syncthreads();

    int buf = 0;
    for (int t = 0; t < nt; ++t) {
        const int s0 = sb + t * 32;
        kSrc0 += 32 * QKV_N; kSrc1 += 32 * QKV_N;
        vSrc0 += 32;         vSrc1 += 32;
        if (t + 1 < nt) {
            gload16(kSrc0, &Klds[buf ^ 1][tid * 8]);
            gload16(kSrc1, &Klds[buf ^ 1][2048 + tid * 8]);
            gload16(vSrc0, &Vlds[buf ^ 1][tid * 8]);
            gload16(vSrc1, &Vlds[buf ^ 1][2048 + tid * 8]);
        }

        f32x4 sacc[2];
        sacc[0] = f32x4{0.f, 0.f, 0.f, 0.f};
        sacc[1] = f32x4{0.f, 0.f, 0.f, 0.f};
        #pragma unroll
        for (int kk = 0; kk < 4; ++kk) {
            bf16x8 ak0 = *(const bf16x8*)&Klds[buf][kk * 512 + lk * 128 + lr * 8];
            bf16x8 ak1 = *(const bf16x8*)&Klds[buf][2048 + kk * 512 + lk * 128 + lr * 8];
            sacc[0] = __builtin_amdgcn_mfma_f32_16x16x32_bf16(ak0, aq[kk], sacc[0], 0, 0, 0);
            sacc[1] = __builtin_amdgcn_mfma_f32_16x16x32_bf16(ak1, aq[kk], sacc[1], 0, 0, 0);
        }

        float x[8];
        #pragma unroll
        for (int st = 0; st < 2; ++st)
            #pragma unroll
            for (int jj = 0; jj < 4; ++jj)
                x[st * 4 + jj] = sacc[st][jj];

        const bool fast = (s0 >= seg_last) && (s0 + 31 <= q0);
        if (!fast) {
            #pragma unroll
            for (int st = 0; st < 2; ++st)
                #pragma unroll
                for (int jj = 0; jj < 4; ++jj) {
                    const int sg = s0 + st * 16 + lk * 4 + jj;
                    const bool vld = (sg >= seg_lo) && (sg <= qg);
                    x[st * 4 + jj] = vld ? x[st * 4 + jj] : -3e38f;
                }
        }

        float mx = fmaxf(fmaxf(fmaxf(x[0], x[1]), fmaxf(x[2], x[3])),
                         fmaxf(fmaxf(x[4], x[5]), fmaxf(x[6], x[7])));
        mx = fmaxf(mx, __shfl_xor(mx, 16));
        mx = fmaxf(mx, __shfl_xor(mx, 32));
        const float mn = fmaxf(m_r, mx);
        const float al = __expf(m_r - mn);
        float p[8], ps = 0.f;
        #pragma unroll
        for (int i = 0; i < 8; ++i) { p[i] = __expf(x[i] - mn); ps += p[i]; }
        ps += __shfl_xor(ps, 16);
        ps += __shfl_xor(ps, 32);
        l_r = l_r * al + ps;
        m_r = mn;

        #pragma unroll
        for (int dt = 0; dt < 8; ++dt) {
            oacc[dt][0] *= al; oacc[dt][1] *= al;
            oacc[dt][2] *= al; oacc[dt][3] *= al;
        }

        int u00 = ((int)f2bf(p[1]) << 16) | f2bf(p[0]);
        int u01 = ((int)f2bf(p[3]) << 16) | f2bf(p[2]);
        int u10 = ((int)f2bf(p[5]) << 16) | f2bf(p[4]);
        int u11 = ((int)f2bf(p[7]) << 16) | f2bf(p[6]);

        const int srcA = (lk & 1) * 32 + lr;
        const int srcB = srcA + 16;
        const bool hi = (lk & 2) != 0;
        int a0 = __shfl(u00, srcA), b0 = __shfl(u10, srcA);
        int a1 = __shfl(u01, srcA), b1 = __shfl(u11, srcA);
        int a2 = __shfl(u00, srcB), b2 = __shfl(u10, srcB);
        int a3 = __shfl(u01, srcB), b3 = __shfl(u11, srcB);
        union { int wds[4]; bf16x8 v; } pf;
        pf.wds[0] = hi ? b0 : a0;
        pf.wds[1] = hi ? b1 : a1;
        pf.wds[2] = hi ? b2 : a2;
        pf.wds[3] = hi ? b3 : a3;

        #pragma unroll
        for (int dt = 0; dt < 8; ++dt) {
            bf16x8 av = *(const bf16x8*)&Vlds[buf][dt * 512 + lk * 128 + lr * 8];
            oacc[dt] = __builtin_amdgcn_mfma_f32_16x16x32_bf16(av, pf.v, oacc[dt], 0, 0, 0);
        }
        __syncthreads();
        buf ^= 1;
    }

    const float inv = 1.f / l_r;
    #pragma unroll
    for (int dt = 0; dt < 8; ++dt) {
        ushort4 o;
        o.x = f2bf(oacc[dt][0] * inv);
        o.y = f2bf(oacc[dt][1] * inv);
        o.z = f2bf(oacc[dt][2] * inv);
        o.w = f2bf(oacc[dt][3] * inv);
        *(ushort4*)&ob[(size_t)qg * (NH * HD) + h * HD + dt * 16 + lk * 4] = o;
    }
}

extern "C" void kernel_launch(void* const* d_in, const int* in_sizes, int n_in,
                              void* d_out, int out_size, void* d_ws, size_t ws_size,
                              hipStream_t stream)
{
    const float* hs       = (const float*)d_in[0];
    const int*   pos      = (const int*)d_in[1];
    const int*   cu       = (const int*)d_in[2];
    const float* inv_freq = (const float*)d_in[3];
    const float* Wq       = (const float*)d_in[4];
    const float* bq       = (const float*)d_in[5];
    const float* Wk       = (const float*)d_in[6];
    const float* bk       = (const float*)d_in[7];
    const float* Wv       = (const float*)d_in[8];
    const float* bv       = (const float*)d_in[9];
    const float* Wo       = (const float*)d_in[10];
    float* out = (float*)d_out;

    unsigned short* hsb   = (unsigned short*)d_ws;          //  8,388,608
    unsigned short* wqkvT = hsb + 8388608;                  //  5,242,880
    unsigned short* wot   = wqkvT + 5242880;                //  4,194,304
    unsigned short* qkvb  = wot + 4194304;                  // 10,485,760
    unsigned short* vtb   = qkvb + 10485760;                //  1,048,576
    unsigned short* obb   = vtb + 1048576;                  //  8,388,608
    float* bqkv = (float*)(obb + 8388608);                  //  2,560 floats

    prep_all<<<dim3(8192 + 9216 + 10), 256, 0, stream>>>(
        hs, hsb, Wq, Wk, Wv, Wo, wqkvT, wot, bq, bk, bv, bqkv);

    gemm8<0><<<dim3((T_TOK / 256) * (QKV_N / 256)), 512, 0, stream>>>(
        hsb, wqkvT, bqkv, qkvb, vtb, QKV_N, HIDDEN);

    rope_kernel<<<dim3(T_TOK / 4), 256, 0, stream>>>(qkvb, pos, inv_freq);

    attn_mfma<<<dim3(64 * NH), 256, 0, stream>>>(qkvb, vtb, cu, obb);

    gemm8<1><<<dim3((T_TOK / 256) * (HIDDEN / 128)), 512, 0, stream>>>(
        obb, wot, nullptr, out, nullptr, HIDDEN, NH * HD);
}